// Round 5
// baseline (38.831 us; speedup 1.0000x reference)
//
#include <hip/hip_runtime.h>

#define HW 128
#define PLANE (HW * HW)      // 16384
#define SCALE 0.17677669529663687f   // 32^-0.5

// 4-way channel split for occupancy: one thread = 4-pixel x-strip x 8 channels.
// lane = strip*2 + h4lo (h4lo picks quads {0..3,8..11} vs {4..7,12..15});
// wave = one image row; waves 0,1 = rows 0,1 of the 2-row tile with channel
// half h4hi=0, waves 2,3 = same rows with h4hi=1. QK logits are reduced
// lane-pair-wise via __shfl_xor(1) (16 ch) then across wave halves via LDS
// (32 ch). PV is channel-parallel (no reduction). All k/v/q loads float4.
// Grid = 4b * 4head * 64 ytiles = 1024 blocks x 256 thr = 4096 waves
// = 16 waves/CU (4/SIMD); __launch_bounds__(256,4) caps VGPR at 128.
__global__ __launch_bounds__(256, 4) void natt3x3_kernel(
    const float* __restrict__ q,
    const float* __restrict__ k,
    const float* __restrict__ v,
    float* __restrict__ out) {
  const int tid   = threadIdx.x;
  const int lane  = tid & 63;
  const int w     = tid >> 6;           // 0..3
  const int row   = w & 1;              // row within 2-row tile
  const int h4hi  = w >> 1;             // 16-channel half of head
  const int h4lo  = lane & 1;           // 4-channel quad selector
  const int strip = lane >> 1;          // 0..31
  const int x0    = strip << 2;
  const int bid   = blockIdx.x;         // ((b*4+head)*64 + ytile)
  const int ytile = bid & 63;
  const int head  = (bid >> 6) & 3;
  const int b     = bid >> 8;
  const int y     = (ytile << 1) | row;

  // thread's 8 channels: chan0 + {0..3} and chan0 + 8 + {0..3},
  // chan0 = head*32 + h4hi*16 + h4lo*4
  const size_t cbase = (size_t)(b * 128 + head * 32 + h4hi * 16 + h4lo * 4) * PLANE;
  const int yx = y * HW + x0;

  int yrow[3];
#pragma unroll
  for (int dy = 0; dy < 3; ++dy) {
    int yy = y + dy - 1; yy = yy < 0 ? 0 : (yy > HW - 1 ? HW - 1 : yy);
    yrow[dy] = yy * HW;
  }

  float l[4][9];
#pragma unroll
  for (int i = 0; i < 4; ++i)
#pragma unroll
    for (int j = 0; j < 9; ++j) l[i][j] = 0.f;

  // ---- QK: two channel-quads (8 channels) ----
#pragma unroll
  for (int qd = 0; qd < 2; ++qd) {
    const float* qg = q + cbase + (size_t)(qd * 8) * PLANE + yx;
    const float* kg = k + cbase + (size_t)(qd * 8) * PLANE;
    float4 qv[4], kv[3][4];
#pragma unroll
    for (int c = 0; c < 4; ++c) {
      qv[c] = *reinterpret_cast<const float4*>(qg + (size_t)c * PLANE);
#pragma unroll
      for (int dy = 0; dy < 3; ++dy)
        kv[dy][c] = *reinterpret_cast<const float4*>(kg + (size_t)c * PLANE + yrow[dy] + x0);
    }
#pragma unroll
    for (int c = 0; c < 4; ++c) {
      const float qa[4] = {qv[c].x * SCALE, qv[c].y * SCALE,
                           qv[c].z * SCALE, qv[c].w * SCALE};
#pragma unroll
      for (int dy = 0; dy < 3; ++dy) {
        float4 kq = kv[dy][c];
        float n0 = __shfl_up(kq.w, 2);     // left neighbor strip
        float n5 = __shfl_down(kq.x, 2);   // right neighbor strip
        const float n[6] = {n0, kq.x, kq.y, kq.z, kq.w, n5};
#pragma unroll
        for (int i = 0; i < 4; ++i)
#pragma unroll
          for (int j = 0; j < 3; ++j)
            l[i][dy * 3 + j] += qa[i] * n[i + j];
      }
    }
  }

  // ---- lane-pair reduce: 8 -> 16 channels ----
#pragma unroll
  for (int i = 0; i < 4; ++i)
#pragma unroll
    for (int j = 0; j < 9; ++j) l[i][j] += __shfl_xor(l[i][j], 1);

  // ---- cross-wave reduce: 16 -> 32 channels (waves w and w^2) ----
  // layout [j][wave][strip]: b32 writes bank = strip -> conflict-free;
  // reads are pair-broadcast -> conflict-free.
  __shared__ float red[36][4][32];
  if (h4lo == 0) {
#pragma unroll
    for (int i = 0; i < 4; ++i)
#pragma unroll
      for (int j = 0; j < 9; ++j)
        red[i * 9 + j][w][strip] = l[i][j];
  }
  __syncthreads();
  {
    const int pw = w ^ 2;
#pragma unroll
    for (int i = 0; i < 4; ++i)
#pragma unroll
      for (int j = 0; j < 9; ++j)
        l[i][j] += red[i * 9 + j][pw][strip];
  }

  // ---- mask + softmax per pixel; fold mask back into weights ----
#pragma unroll
  for (int i = 0; i < 4; ++i) {
    const int xp = x0 + i;
    float mk[9];
#pragma unroll
    for (int dy = 0; dy < 3; ++dy)
#pragma unroll
      for (int dx = 0; dx < 3; ++dx) {
        bool ok = ((unsigned)(y + dy - 1) < (unsigned)HW) &&
                  ((unsigned)(xp + dx - 1) < (unsigned)HW);
        mk[dy * 3 + dx] = ok ? 1.f : 0.f;
      }
    float m = -1e30f;
#pragma unroll
    for (int j = 0; j < 9; ++j) {
      float t = l[i][j] * mk[j];
      l[i][j] = t;
      m = fmaxf(m, t);
    }
    float sum = 0.f;
#pragma unroll
    for (int j = 0; j < 9; ++j) {
      float e = __expf(l[i][j] - m);
      l[i][j] = e;
      sum += e;
    }
    float inv = 1.f / sum;
#pragma unroll
    for (int j = 0; j < 9; ++j) l[i][j] *= inv * mk[j];
  }

  // ---- PV + ReLU + store: two channel-quads ----
  const size_t obase = ((size_t)(b * PLANE + y * HW)) * 128 + head * 32 + h4hi * 16 + h4lo * 4;
#pragma unroll
  for (int qd = 0; qd < 2; ++qd) {
    const float* vg = v + cbase + (size_t)(qd * 8) * PLANE;
    float4 vv[3][4];
#pragma unroll
    for (int c = 0; c < 4; ++c)
#pragma unroll
      for (int dy = 0; dy < 3; ++dy)
        vv[dy][c] = *reinterpret_cast<const float4*>(vg + (size_t)c * PLANE + yrow[dy] + x0);

    float acc[4][4];
#pragma unroll
    for (int i = 0; i < 4; ++i)
#pragma unroll
      for (int c = 0; c < 4; ++c) acc[i][c] = 0.f;
#pragma unroll
    for (int c = 0; c < 4; ++c)
#pragma unroll
      for (int dy = 0; dy < 3; ++dy) {
        float4 vq = vv[dy][c];
        float n0 = __shfl_up(vq.w, 2);
        float n5 = __shfl_down(vq.x, 2);
        const float n[6] = {n0, vq.x, vq.y, vq.z, vq.w, n5};
#pragma unroll
        for (int i = 0; i < 4; ++i)
#pragma unroll
          for (int j = 0; j < 3; ++j)
            acc[i][c] += l[i][dy * 3 + j] * n[i + j];
      }
#pragma unroll
    for (int i = 0; i < 4; ++i) {
      float4 o;
      o.x = fmaxf(acc[i][0], 0.f);
      o.y = fmaxf(acc[i][1], 0.f);
      o.z = fmaxf(acc[i][2], 0.f);
      o.w = fmaxf(acc[i][3], 0.f);
      *reinterpret_cast<float4*>(out + obase + (size_t)(x0 + i) * 128 + qd * 8) = o;
    }
  }
}

extern "C" void kernel_launch(void* const* d_in, const int* in_sizes, int n_in,
                              void* d_out, int out_size, void* d_ws, size_t ws_size,
                              hipStream_t stream) {
  const float* q = (const float*)d_in[0];
  const float* k = (const float*)d_in[1];
  const float* v = (const float*)d_in[2];
  float* out = (float*)d_out;
  // grid: B(4) * heads(4) * ytiles(64) = 1024 blocks, 256 threads
  natt3x3_kernel<<<1024, 256, 0, stream>>>(q, k, v, out);
}